// Round 1
// 585.202 us; speedup vs baseline: 1.0548x; 1.0548x over previous
//
#include <hip/hip_runtime.h>
#include <hip/hip_bf16.h>
#include <hip/hip_fp16.h>

#define B2F(x) __bfloat162float(x)
#define F2B(x) __float2bfloat16(x)

typedef __bf16 bf16x8 __attribute__((ext_vector_type(8)));
typedef float floatx4 __attribute__((ext_vector_type(4)));

static constexpr int MROWS = 50176;   // 512 windows * 98 tokens
static constexpr int CDIM  = 256;
static constexpr int MCHUNK = 25088;  // MROWS / 2 for MLP chunking

enum { MODE_BF16 = 0, MODE_VALOFFAW = 1, MODE_REVERSE = 3, MODE_GELU = 4, MODE_FC2 = 5 };

#if defined(__has_builtin)
#if __has_builtin(__builtin_amdgcn_global_load_lds)
#define HAS_GLL 1
#endif
#endif
#ifndef HAS_GLL
#define HAS_GLL 0
#endif

// ---------------- helpers ----------------

__device__ __forceinline__ float block_sum256(float v, float* s4, int tid) {
#pragma unroll
    for (int off = 32; off > 0; off >>= 1) v += __shfl_down(v, off, 64);
    if ((tid & 63) == 0) s4[tid >> 6] = v;
    __syncthreads();
    float r = s4[0] + s4[1] + s4[2] + s4[3];
    __syncthreads();
    return r;
}

__device__ __forceinline__ void win_decode(int r, int& tok) {
    int w = r / 98, n = r - w * 98;
    int dB = w >> 6, hB = (w >> 3) & 7, wB = w & 7;
    int z = n / 49, n2 = n - z * 49, yy = n2 / 7, xx = n2 - yy * 7;
    tok = ((dB * 2 + z) * 56 + hB * 7 + yy) * 56 + wB * 7 + xx;
}

__device__ __forceinline__ float bf2f(unsigned short u) {
    return __uint_as_float(((unsigned)u) << 16);
}

// ---------------- fused weight transpose (f32 -> bf16, (K,N)->(N,K)) ----------------

__global__ __launch_bounds__(256) void transpose_all(
    const float* __restrict__ val_w, const float* __restrict__ off_w,
    const float* __restrict__ aw_w,  const float* __restrict__ out_w,
    const float* __restrict__ proj_w, const float* __restrict__ fc1_w,
    const float* __restrict__ fc2_w,
    __hip_bfloat16* __restrict__ valT, __hip_bfloat16* __restrict__ offawT,
    __hip_bfloat16* __restrict__ outT, __hip_bfloat16* __restrict__ projT,
    __hip_bfloat16* __restrict__ fc1T, __hip_bfloat16* __restrict__ fc2T) {
    int bid = blockIdx.x;
    const float* src; __hip_bfloat16* dst; int K, N, base;
    if (bid < 256)       { src = val_w;  dst = valT;           K = 256;  N = 256;  base = 0; }
    else if (bid < 352)  { src = off_w;  dst = offawT;         K = 256;  N = 96;   base = 256; }
    else if (bid < 384)  { src = aw_w;   dst = offawT + 96*256; K = 256; N = 32;   base = 352; }
    else if (bid < 640)  { src = out_w;  dst = outT;           K = 256;  N = 256;  base = 384; }
    else if (bid < 896)  { src = proj_w; dst = projT;          K = 256;  N = 256;  base = 640; }
    else if (bid < 1920) { src = fc1_w;  dst = fc1T;           K = 256;  N = 1024; base = 896; }
    else                 { src = fc2_w;  dst = fc2T;           K = 1024; N = 256;  base = 1920; }
    int i = (bid - base) * 256 + threadIdx.x;
    if (i >= K * N) return;
    int nn = i / K, kk = i - nn * K;
    dst[(size_t)nn * K + kk] = F2B(src[(size_t)kk * N + nn]);
}

// ---------------- diag (PositionEmbeddingSine) + colsum of off/aw weight ----------------

__global__ __launch_bounds__(256) void diag_colsum_kernel(
    const float* __restrict__ mask, float* __restrict__ diag,
    const __hip_bfloat16* __restrict__ wT, float* __restrict__ csum) {
    if (blockIdx.x == gridDim.x - 1) {
        int n = threadIdx.x;
        if (n < 128) {
            float s = 0.f;
            for (int k = 0; k < 256; ++k) s += B2F(wT[n * 256 + k]);
            csum[n] = s;
        }
        return;
    }
    int r = blockIdx.x * 256 + threadIdx.x;
    int n = r % 98;
    int z = n / 49, n2 = n - z * 49, yy = n2 / 7, xx = n2 - yy * 7;
    const float* mb = mask + (size_t)r * 98;
    float m = mb[z * 49 + yy * 7 + xx];
    float sz = 0.f, sy = 0.f, sx = 0.f;
    for (int k = 0; k <= z; ++k)  sz += mb[k * 49 + yy * 7 + xx];
    for (int k = 0; k <= yy; ++k) sy += mb[z * 49 + k * 7 + xx];
    for (int k = 0; k <= xx; ++k) sx += mb[z * 49 + yy * 7 + k];
    const float PI = 3.14159265358979323846f;
    diag[r] = m * (sinf(sx * m / PI) + sinf(sy * m) + sz * m / PI);
}

// ---------------- LayerNorms ----------------

__global__ __launch_bounds__(256) void ln1_kernel(
    const float* __restrict__ x,
    const float* __restrict__ g, const float* __restrict__ b,
    __hip_bfloat16* __restrict__ xw) {
    __shared__ float s4[4];
    int r = blockIdx.x, c = threadIdx.x;
    int tok; win_decode(r, tok);
    float v = x[(size_t)tok * CDIM + c];
    float mean = block_sum256(v, s4, c) * (1.f / 256.f);
    float d = v - mean;
    float var = block_sum256(d * d, s4, c) * (1.f / 256.f);
    xw[(size_t)r * CDIM + c] = F2B(d * rsqrtf(var + 1e-5f) * g[c] + b[c]);
}

__global__ __launch_bounds__(256) void ln_a_kernel(
    const __hip_bfloat16* __restrict__ xw, const __hip_bfloat16* __restrict__ attn,
    const float* __restrict__ g, const float* __restrict__ b,
    __hip_bfloat16* a2) {
    __shared__ float s4[4];
    int r = blockIdx.x, c = threadIdx.x;
    size_t i = (size_t)r * CDIM + c;
    float t = B2F(xw[i]) + B2F(attn[i]);
    float mean = block_sum256(t, s4, c) * (1.f / 256.f);
    float d = t - mean;
    float var = block_sum256(d * d, s4, c) * (1.f / 256.f);
    a2[i] = F2B(d * rsqrtf(var + 1e-5f) * g[c] + b[c]);
}

__global__ __launch_bounds__(256) void ln2_kernel(
    const float* __restrict__ xres,
    const float* __restrict__ g, const float* __restrict__ b,
    __hip_bfloat16* __restrict__ hin) {
    __shared__ float s4[4];
    int r = blockIdx.x, c = threadIdx.x;
    size_t i = (size_t)r * CDIM + c;
    float v = xres[i];
    float mean = block_sum256(v, s4, c) * (1.f / 256.f);
    float d = v - mean;
    float var = block_sum256(d * d, s4, c) * (1.f / 256.f);
    hin[i] = F2B(d * rsqrtf(var + 1e-5f) * g[c] + b[c]);
}

// ---------------- fused sampling: prep (softmax + corner wgt/idx) + LDS gather ----------------
// One block per window. value window (98x256 bf16 = 49 KB) + corner weights
// (98x8x32 f16 = 49 KB) + indices (24.5 KB) all live in LDS (125 KB total).
// Eliminates the 50 MB wgt/idxb HBM round-trip and converts the latency-bound
// global gather into ds_read_b64 (bank = 2*c4 mod 32: conflict-free per 16-lane group).

__global__ __launch_bounds__(512) void sample_fused(
    const __half* __restrict__ offaw,          // M x 128 (96 off | 32 aw), f16
    const __hip_bfloat16* __restrict__ value,  // M x 256
    __hip_bfloat16* __restrict__ ai) {         // M x 256
    __shared__ __align__(16) __hip_bfloat16 vs[98 * 256];   // 50176 B
    __shared__ __align__(16) __half ws[98 * 8 * 32];        // 50176 B
    __shared__ __align__(16) unsigned char isb[98 * 8 * 32]; // 25088 B
    const int tid = threadIdx.x;
    const int w = blockIdx.x;

    // Phase A: stage value window into LDS (3136 x uint4)
    {
        const uint4* vsrc = (const uint4*)(value + (size_t)w * 98 * CDIM);
        uint4* vdst = (uint4*)vs;
#pragma unroll 2
        for (int i = tid; i < 98 * CDIM / 8; i += 512) vdst[i] = vsrc[i];
    }

    // Phase B: per (row,head) softmax over 4 points + 32 corner weights/indices
    for (int u = tid; u < 98 * 8; u += 512) {
        int r = u >> 3, h = u & 7;
        int z = r / 49, n2 = r - z * 49, yy = n2 / 7, xx = n2 - yy * 7;
        const __half* orow = offaw + ((size_t)w * 98 + r) * 128;
        float l0 = __half2float(orow[96 + h * 4 + 0]);
        float l1 = __half2float(orow[96 + h * 4 + 1]);
        float l2 = __half2float(orow[96 + h * 4 + 2]);
        float l3 = __half2float(orow[96 + h * 4 + 3]);
        float mx = fmaxf(fmaxf(l0, l1), fmaxf(l2, l3));
        float e[4];
        e[0] = __expf(l0 - mx); e[1] = __expf(l1 - mx); e[2] = __expf(l2 - mx); e[3] = __expf(l3 - mx);
        float inv = 1.f / (e[0] + e[1] + e[2] + e[3]);
        __half wl[32];
        unsigned char il[32];
#pragma unroll
        for (int p = 0; p < 4; ++p) {
            float ox = __half2float(orow[h * 12 + p * 3 + 0]);
            float oy = __half2float(orow[h * 12 + p * 3 + 1]);
            float oz = __half2float(orow[h * 12 + p * 3 + 2]);
            // px = loc_x*WW - 0.5 == x + off_x (0.5 terms cancel); same for y,z
            float px = (float)xx + ox, py = (float)yy + oy, pz = (float)z + oz;
            float fx0 = floorf(px), fy0 = floorf(py), fz0 = floorf(pz);
            int ix = (int)fx0, iy = (int)fy0, iz = (int)fz0;
            float fx = px - fx0, fy = py - fy0, fz = pz - fz0;
            float wp = e[p] * inv;
            int j = 0;
#pragma unroll
            for (int dz = 0; dz < 2; ++dz) {
                int zi = iz + dz;
                float wz = dz ? fz : 1.f - fz;
#pragma unroll
                for (int dy = 0; dy < 2; ++dy) {
                    int yi = iy + dy;
                    float wy = dy ? fy : 1.f - fy;
#pragma unroll
                    for (int dx = 0; dx < 2; ++dx) {
                        int xi = ix + dx;
                        float wxw = dx ? fx : 1.f - fx;
                        bool valid = (zi >= 0) & (zi < 2) & (yi >= 0) & (yi < 7) & (xi >= 0) & (xi < 7);
                        float wc = valid ? wp * wz * wy * wxw : 0.f;
                        int zc = min(max(zi, 0), 1), yc = min(max(yi, 0), 6), xc = min(max(xi, 0), 6);
                        wl[p * 8 + j] = __float2half(wc);
                        il[p * 8 + j] = (unsigned char)(zc * 49 + yc * 7 + xc);
                        ++j;
                    }
                }
            }
        }
        uint4* wd = (uint4*)(ws + (size_t)u * 32);
        const uint4* ws4 = (const uint4*)wl;
#pragma unroll
        for (int q = 0; q < 4; ++q) wd[q] = ws4[q];
        uint4* idd = (uint4*)(isb + (size_t)u * 32);
        const uint4* is4 = (const uint4*)il;
#pragma unroll
        for (int q = 0; q < 2; ++q) idd[q] = is4[q];
    }
    __syncthreads();

    // Phase C: gather + weighted sum, 4 channels/thread, 8 rows per pass
    const int c4 = tid & 63;
    const int h = c4 >> 3;
    const int c0 = c4 * 4;
    for (int r = tid >> 6; r < 98; r += 8) {
        const __half* wrow = ws + ((size_t)((r << 3) + h)) * 32;
        const unsigned char* irow = isb + ((size_t)((r << 3) + h)) * 32;
        float a0 = 0.f, a1 = 0.f, a2 = 0.f, a3 = 0.f;
#pragma unroll
        for (int p = 0; p < 4; ++p) {
            uint4 wq = *(const uint4*)(wrow + p * 8);
            uint2 iq = *(const uint2*)(irow + p * 8);
            const __half* wh = (const __half*)&wq;
            const unsigned char* ib = (const unsigned char*)&iq;
#pragma unroll
            for (int j = 0; j < 8; ++j) {
                float wj = __half2float(wh[j]);
                ushort4 v = *(const ushort4*)(vs + (size_t)ib[j] * CDIM + c0);
                a0 += wj * bf2f(v.x);
                a1 += wj * bf2f(v.y);
                a2 += wj * bf2f(v.z);
                a3 += wj * bf2f(v.w);
            }
        }
        __hip_bfloat16 ob[4] = { F2B(a0), F2B(a1), F2B(a2), F2B(a3) };
        *(ushort4*)(ai + ((size_t)w * 98 + r) * CDIM + c0) = *(const ushort4*)ob;
    }
}

// ---------------- MFMA GEMM (double-buffered async staging) ----------------
// C[M,N] = A[M,K] * Bt[N,K]^T + bias, epilogue per MODE.

template <int MODE>
__global__ __launch_bounds__(256) void gemm_bt(
    const __hip_bfloat16* __restrict__ A,
    const __hip_bfloat16* __restrict__ Bt,
    const int N, const int K,
    const float* __restrict__ bias0,
    const float* __restrict__ bias1,
    const float* __restrict__ bias2,
    void* C,
    void* extra,
    const void* extra2,
    const float* __restrict__ csum) {
    __shared__ __align__(16) __hip_bfloat16 As[2][128 * 32];
    __shared__ __align__(16) __hip_bfloat16 Bs[2][128 * 32];
    const int tid  = threadIdx.x;
    const int lane = tid & 63;
    const int wave = tid >> 6;
    const int wm = (wave >> 1) * 64;
    const int wn = (wave & 1) * 64;
    const int row0 = blockIdx.x * 128;
    const int col0 = blockIdx.y * 128;
    const int l15 = lane & 15;
    const int quad = lane >> 4;

    floatx4 acc[4][4] = {};

    const int sr = tid >> 2;
    const int sk = (tid & 3) * 8;

    const __hip_bfloat16* Ab = A + (size_t)row0 * K + sr * (size_t)K + sk;
    const __hip_bfloat16* Bb = Bt + (size_t)col0 * K + sr * (size_t)K + sk;
    const size_t half64 = (size_t)64 * K;

    auto stage = [&](int buf, int k0) {
#if HAS_GLL
        __builtin_amdgcn_global_load_lds(
            (const __attribute__((address_space(1))) void*)(Ab + k0),
            (__attribute__((address_space(3))) void*)(&As[buf][sr * 32 + sk]), 16, 0, 0);
        __builtin_amdgcn_global_load_lds(
            (const __attribute__((address_space(1))) void*)(Ab + half64 + k0),
            (__attribute__((address_space(3))) void*)(&As[buf][(sr + 64) * 32 + sk]), 16, 0, 0);
        __builtin_amdgcn_global_load_lds(
            (const __attribute__((address_space(1))) void*)(Bb + k0),
            (__attribute__((address_space(3))) void*)(&Bs[buf][sr * 32 + sk]), 16, 0, 0);
        __builtin_amdgcn_global_load_lds(
            (const __attribute__((address_space(1))) void*)(Bb + half64 + k0),
            (__attribute__((address_space(3))) void*)(&Bs[buf][(sr + 64) * 32 + sk]), 16, 0, 0);
#else
        *reinterpret_cast<uint4*>(&As[buf][sr * 32 + sk]) = *reinterpret_cast<const uint4*>(Ab + k0);
        *reinterpret_cast<uint4*>(&As[buf][(sr + 64) * 32 + sk]) = *reinterpret_cast<const uint4*>(Ab + half64 + k0);
        *reinterpret_cast<uint4*>(&Bs[buf][sr * 32 + sk]) = *reinterpret_cast<const uint4*>(Bb + k0);
        *reinterpret_cast<uint4*>(&Bs[buf][(sr + 64) * 32 + sk]) = *reinterpret_cast<const uint4*>(Bb + half64 + k0);
#endif
    };

    const int nk = K >> 5;
    stage(0, 0);
    for (int t = 0; t < nk; ++t) {
        __syncthreads();                       // drains vmcnt: buffer t&1 is ready
        if (t + 1 < nk) stage((t + 1) & 1, (t + 1) * 32);   // async fill of other buffer
        const __hip_bfloat16* Asb = As[t & 1];
        const __hip_bfloat16* Bsb = Bs[t & 1];
        bf16x8 af[4], bfg[4];
#pragma unroll
        for (int i = 0; i < 4; ++i)
            af[i] = *reinterpret_cast<const bf16x8*>(&Asb[(wm + i * 16 + l15) * 32 + quad * 8]);
#pragma unroll
        for (int j = 0; j < 4; ++j)
            bfg[j] = *reinterpret_cast<const bf16x8*>(&Bsb[(wn + j * 16 + l15) * 32 + quad * 8]);
#pragma unroll
        for (int i = 0; i < 4; ++i)
#pragma unroll
            for (int j = 0; j < 4; ++j)
                acc[i][j] = __builtin_amdgcn_mfma_f32_16x16x32_bf16(af[i], bfg[j], acc[i][j], 0, 0, 0);
    }

#pragma unroll
    for (int i = 0; i < 4; ++i) {
#pragma unroll
        for (int j = 0; j < 4; ++j) {
#pragma unroll
            for (int rr = 0; rr < 4; ++rr) {
                int row = row0 + wm + i * 16 + quad * 4 + rr;
                int col = col0 + wn + j * 16 + l15;
                float v = acc[i][j][rr];
                if constexpr (MODE == MODE_BF16) {
                    v += bias0[col];
                    ((__hip_bfloat16*)C)[(size_t)row * N + col] = F2B(v);
                } else if constexpr (MODE == MODE_VALOFFAW) {
                    // cols [0,256): value (bf16, ld 256). cols [256,384): offaw (f16, ld 128)
                    if (col < 256) {
                        v += bias0[col];
                        ((__hip_bfloat16*)C)[(size_t)row * 256 + col] = F2B(v);
                    } else {
                        int c2 = col - 256;
                        const float* diag = (const float*)extra2;
                        v += (c2 < 96 ? bias1[c2] : bias2[c2 - 96]);
                        v += diag[row] * csum[c2];   // q = xw + diag folded in
                        ((__half*)extra)[(size_t)row * 128 + c2] = __float2half(v);
                    }
                } else if constexpr (MODE == MODE_REVERSE) {
                    v += bias0[col];
                    int tok; win_decode(row, tok);
                    const float* xin = (const float*)extra2;   // original x, f32
                    ((float*)C)[(size_t)tok * CDIM + col] = xin[(size_t)tok * CDIM + col] + v;
                } else if constexpr (MODE == MODE_GELU) {
                    v += bias0[col];
                    // gelu_tanh == v * sigmoid(2t)
                    float t2 = 1.5957691216057308f * (v + 0.044715f * v * v * v);
                    v = v / (1.f + __expf(-t2));
                    ((__hip_bfloat16*)C)[(size_t)row * N + col] = F2B(v);
                } else {  // MODE_FC2: out = xres + A@fc2 + b, f32 in-place on d_out
                    v += bias0[col];
                    const float* xres = (const float*)extra2;
                    v += xres[(size_t)row * CDIM + col];
                    ((float*)C)[(size_t)row * CDIM + col] = v;
                }
            }
        }
    }
}

// ---------------- host launcher ----------------

extern "C" void kernel_launch(void* const* d_in, const int* in_sizes, int n_in,
                              void* d_out, int out_size, void* d_ws, size_t ws_size,
                              hipStream_t stream) {
    const float* x      = (const float*)d_in[0];
    const float* mask   = (const float*)d_in[1];
    const float* n1g    = (const float*)d_in[2];
    const float* n1b    = (const float*)d_in[3];
    const float* val_w  = (const float*)d_in[4];
    const float* val_b  = (const float*)d_in[5];
    const float* off_w  = (const float*)d_in[6];
    const float* off_b  = (const float*)d_in[7];
    const float* aw_w   = (const float*)d_in[8];
    const float* aw_b   = (const float*)d_in[9];
    const float* out_w  = (const float*)d_in[10];
    const float* out_b  = (const float*)d_in[11];
    const float* ang    = (const float*)d_in[12];
    const float* anb    = (const float*)d_in[13];
    const float* proj_w = (const float*)d_in[14];
    const float* proj_b = (const float*)d_in[15];
    const float* n2g    = (const float*)d_in[16];
    const float* n2b    = (const float*)d_in[17];
    const float* fc1_w  = (const float*)d_in[18];
    const float* fc1_b  = (const float*)d_in[19];
    const float* fc2_w  = (const float*)d_in[20];
    const float* fc2_b  = (const float*)d_in[21];

    char* ws = (char*)d_ws;
    size_t o = 0;
    auto alloc = [&](size_t bytes) {
        size_t r = o;
        o += (bytes + 255) & ~(size_t)255;
        return r;
    };
    const size_t M = MROWS;
    const size_t REGION_B = M * 128 * 2 + M * 256 * 2 + M * 256 * 2;  // offaw + ai + slack (hbuf reuse)

    __hip_bfloat16* valT    = (__hip_bfloat16*)(ws + alloc(256 * 256 * 2));
    __hip_bfloat16* offawT  = (__hip_bfloat16*)(ws + alloc(128 * 256 * 2));  // contiguous after valT
    __hip_bfloat16* outT    = (__hip_bfloat16*)(ws + alloc(256 * 256 * 2));
    __hip_bfloat16* projT   = (__hip_bfloat16*)(ws + alloc(256 * 256 * 2));
    __hip_bfloat16* fc1T    = (__hip_bfloat16*)(ws + alloc(1024 * 256 * 2));
    __hip_bfloat16* fc2T    = (__hip_bfloat16*)(ws + alloc(256 * 1024 * 2));
    float*          csum    = (float*)(ws + alloc(128 * 4));
    float*          diag    = (float*)(ws + alloc(M * 4));
    char*           slab1   = ws + alloc(M * 256 * 2);                 // xw -> a2 -> hin
    char*           region  = ws + alloc(REGION_B);                    // multi-use
    (void)ws_size; (void)in_sizes; (void)n_in; (void)out_size;

    __hip_bfloat16* xw    = (__hip_bfloat16*)slab1;
    __hip_bfloat16* a2    = (__hip_bfloat16*)slab1;
    __hip_bfloat16* hin   = (__hip_bfloat16*)slab1;
    __half*         offaw = (__half*)region;                           // M x 128 f16
    __hip_bfloat16* ai    = (__hip_bfloat16*)(region + M * 128 * 2);   // M x 256 bf16
    __hip_bfloat16* hbuf  = (__hip_bfloat16*)region;                   // MLP chunk activation (offaw/ai dead)
    __hip_bfloat16* value = (__hip_bfloat16*)d_out;                    // bf16 scratch
    __hip_bfloat16* attn  = (__hip_bfloat16*)d_out;                    // bf16 scratch
    float*          xres  = (float*)d_out;                             // f32 trunk

    dim3 blk(256);
    hipLaunchKernelGGL(transpose_all, dim3(2944), blk, 0, stream,
                       val_w, off_w, aw_w, out_w, proj_w, fc1_w, fc2_w,
                       valT, offawT, outT, projT, fc1T, fc2T);
    hipLaunchKernelGGL(diag_colsum_kernel, dim3(MROWS / 256 + 1), blk, 0, stream,
                       mask, diag, offawT, csum);

    // 1. xw = LN1(x) windowed          (slab1)
    hipLaunchKernelGGL(ln1_kernel, dim3(MROWS), blk, 0, stream, x, n1g, n1b, xw);
    // 2+3 merged. N=384 over [valT|offawT]: value -> d_out bf16, offaw -> region f16
    hipLaunchKernelGGL((gemm_bt<MODE_VALOFFAW>), dim3(MROWS / 128, 3), blk, 0, stream,
                       xw, valT, 384, 256, val_b, off_b, aw_b,
                       (void*)value, (void*)offaw, (const void*)diag, csum);
    // 4. ai = fused prep + LDS-gather sample(value)   (region)
    hipLaunchKernelGGL(sample_fused, dim3(MROWS / 98), dim3(512), 0, stream,
                       offaw, value, ai);
    // 5. attn = ai @ out_w + out_b     (d_out bf16 scratch; value dead)
    hipLaunchKernelGGL((gemm_bt<MODE_BF16>), dim3(MROWS / 128, 2), blk, 0, stream,
                       ai, outT, 256, 256, out_b, (const float*)nullptr, (const float*)nullptr,
                       (void*)attn, (void*)nullptr, (const void*)nullptr, (const float*)nullptr);
    // 6. a2 = LN(xw + attn)            (slab1, in-place over xw)
    hipLaunchKernelGGL(ln_a_kernel, dim3(MROWS), blk, 0, stream, xw, attn, ang, anb, a2);
    // 7. xres = x + reverse(a2 @ proj + b)   (d_out f32, token order; attn dead)
    hipLaunchKernelGGL((gemm_bt<MODE_REVERSE>), dim3(MROWS / 128, 2), blk, 0, stream,
                       a2, projT, 256, 256, proj_b, (const float*)nullptr, (const float*)nullptr,
                       (void*)xres, (void*)nullptr, (const void*)x, (const float*)nullptr);
    // 8. hin = LN2(xres)               (slab1; a2 dead)
    hipLaunchKernelGGL(ln2_kernel, dim3(MROWS), blk, 0, stream, xres, n2g, n2b, hin);
    // 9. MLP in 2 row-chunks; fc2 adds xres in-place on d_out (f32, same element)
    for (int c = 0; c < 2; ++c) {
        const __hip_bfloat16* hin_c = hin + (size_t)c * MCHUNK * 256;
        float*                out_c = (float*)d_out + (size_t)c * MCHUNK * 256;
        hipLaunchKernelGGL((gemm_bt<MODE_GELU>), dim3(MCHUNK / 128, 8), blk, 0, stream,
                           hin_c, fc1T, 1024, 256, fc1_b, (const float*)nullptr, (const float*)nullptr,
                           (void*)hbuf, (void*)nullptr, (const void*)nullptr, (const float*)nullptr);
        hipLaunchKernelGGL((gemm_bt<MODE_FC2>), dim3(MCHUNK / 128, 2), blk, 0, stream,
                           hbuf, fc2T, 256, 1024, fc2_b, (const float*)nullptr, (const float*)nullptr,
                           (void*)out_c, (void*)nullptr, (const void*)out_c, (const float*)nullptr);
    }
}

// Round 2
// 508.295 us; speedup vs baseline: 1.2144x; 1.1513x over previous
//
#include <hip/hip_runtime.h>
#include <hip/hip_bf16.h>
#include <hip/hip_fp16.h>

#define B2F(x) __bfloat162float(x)
#define F2B(x) __float2bfloat16(x)

typedef __bf16 bf16x8 __attribute__((ext_vector_type(8)));
typedef float floatx4 __attribute__((ext_vector_type(4)));

static constexpr int MROWS = 50176;   // 512 windows * 98 tokens
static constexpr int CDIM  = 256;
static constexpr int MCHUNK = 25088;  // MROWS / 2 for MLP chunking

enum { MODE_BF16 = 0, MODE_VALOFFAW = 1, MODE_REVERSE = 3, MODE_GELU = 4, MODE_FC2 = 5 };

#if defined(__has_builtin)
#if __has_builtin(__builtin_amdgcn_global_load_lds)
#define HAS_GLL 1
#endif
#endif
#ifndef HAS_GLL
#define HAS_GLL 0
#endif

// ---------------- helpers ----------------

__device__ __forceinline__ void win_decode(int r, int& tok) {
    int w = r / 98, n = r - w * 98;
    int dB = w >> 6, hB = (w >> 3) & 7, wB = w & 7;
    int z = n / 49, n2 = n - z * 49, yy = n2 / 7, xx = n2 - yy * 7;
    tok = ((dB * 2 + z) * 56 + hB * 7 + yy) * 56 + wB * 7 + xx;
}

__device__ __forceinline__ float bf2f(unsigned short u) {
    return __uint_as_float(((unsigned)u) << 16);
}

__device__ __forceinline__ float wave_sum64(float v) {
#pragma unroll
    for (int off = 32; off > 0; off >>= 1) v += __shfl_xor(v, off, 64);
    return v;
}

// ---------------- fused weight transpose (f32 -> bf16, (K,N)->(N,K)) ----------------

__global__ __launch_bounds__(256) void transpose_all(
    const float* __restrict__ val_w, const float* __restrict__ off_w,
    const float* __restrict__ aw_w,  const float* __restrict__ out_w,
    const float* __restrict__ proj_w, const float* __restrict__ fc1_w,
    const float* __restrict__ fc2_w,
    __hip_bfloat16* __restrict__ valT, __hip_bfloat16* __restrict__ offawT,
    __hip_bfloat16* __restrict__ outT, __hip_bfloat16* __restrict__ projT,
    __hip_bfloat16* __restrict__ fc1T, __hip_bfloat16* __restrict__ fc2T) {
    int bid = blockIdx.x;
    const float* src; __hip_bfloat16* dst; int K, N, base;
    if (bid < 256)       { src = val_w;  dst = valT;           K = 256;  N = 256;  base = 0; }
    else if (bid < 352)  { src = off_w;  dst = offawT;         K = 256;  N = 96;   base = 256; }
    else if (bid < 384)  { src = aw_w;   dst = offawT + 96*256; K = 256; N = 32;   base = 352; }
    else if (bid < 640)  { src = out_w;  dst = outT;           K = 256;  N = 256;  base = 384; }
    else if (bid < 896)  { src = proj_w; dst = projT;          K = 256;  N = 256;  base = 640; }
    else if (bid < 1920) { src = fc1_w;  dst = fc1T;           K = 256;  N = 1024; base = 896; }
    else                 { src = fc2_w;  dst = fc2T;           K = 1024; N = 256;  base = 1920; }
    int i = (bid - base) * 256 + threadIdx.x;
    if (i >= K * N) return;
    int nn = i / K, kk = i - nn * K;
    dst[(size_t)nn * K + kk] = F2B(src[(size_t)kk * N + nn]);
}

// ---------------- diag (PositionEmbeddingSine) + colsum of off/aw weight ----------------

__global__ __launch_bounds__(256) void diag_colsum_kernel(
    const float* __restrict__ mask, float* __restrict__ diag,
    const __hip_bfloat16* __restrict__ wT, float* __restrict__ csum) {
    if (blockIdx.x == gridDim.x - 1) {
        int n = threadIdx.x;
        if (n < 128) {
            float s = 0.f;
            for (int k = 0; k < 256; ++k) s += B2F(wT[n * 256 + k]);
            csum[n] = s;
        }
        return;
    }
    int r = blockIdx.x * 256 + threadIdx.x;
    int n = r % 98;
    int z = n / 49, n2 = n - z * 49, yy = n2 / 7, xx = n2 - yy * 7;
    const float* mb = mask + (size_t)r * 98;
    float m = mb[z * 49 + yy * 7 + xx];
    float sz = 0.f, sy = 0.f, sx = 0.f;
    for (int k = 0; k <= z; ++k)  sz += mb[k * 49 + yy * 7 + xx];
    for (int k = 0; k <= yy; ++k) sy += mb[z * 49 + k * 7 + xx];
    for (int k = 0; k <= xx; ++k) sx += mb[z * 49 + yy * 7 + k];
    const float PI = 3.14159265358979323846f;
    diag[r] = m * (sinf(sx * m / PI) + sinf(sy * m) + sz * m / PI);
}

// ---------------- LayerNorms (wave-per-row, no barriers, no LDS) ----------------
// One 64-lane wave owns a 256-channel row: float4/ushort4 per lane, 6-step
// __shfl_xor butterfly reductions entirely in-register. 4 rows per block.

__global__ __launch_bounds__(256) void ln1_kernel(
    const float* __restrict__ x,
    const float* __restrict__ g, const float* __restrict__ b,
    __hip_bfloat16* __restrict__ xw) {
    const int lane = threadIdx.x & 63;
    const int r = blockIdx.x * 4 + (threadIdx.x >> 6);
    int tok; win_decode(r, tok);
    const int c0 = lane * 4;
    float4 v = *(const float4*)(x + (size_t)tok * CDIM + c0);
    float mean = wave_sum64(v.x + v.y + v.z + v.w) * (1.f / 256.f);
    float dx = v.x - mean, dy = v.y - mean, dz = v.z - mean, dw = v.w - mean;
    float var = wave_sum64(dx * dx + dy * dy + dz * dz + dw * dw) * (1.f / 256.f);
    float rstd = rsqrtf(var + 1e-5f);
    float4 gg = *(const float4*)(g + c0);
    float4 bb = *(const float4*)(b + c0);
    __hip_bfloat16 ob[4] = { F2B(dx * rstd * gg.x + bb.x), F2B(dy * rstd * gg.y + bb.y),
                             F2B(dz * rstd * gg.z + bb.z), F2B(dw * rstd * gg.w + bb.w) };
    *(ushort4*)(xw + (size_t)r * CDIM + c0) = *(const ushort4*)ob;
}

__global__ __launch_bounds__(256) void ln_a_kernel(
    const __hip_bfloat16* __restrict__ xw, const __hip_bfloat16* __restrict__ attn,
    const float* __restrict__ g, const float* __restrict__ b,
    __hip_bfloat16* a2) {
    const int lane = threadIdx.x & 63;
    const int r = blockIdx.x * 4 + (threadIdx.x >> 6);
    const int c0 = lane * 4;
    const size_t base = (size_t)r * CDIM + c0;
    ushort4 xv = *(const ushort4*)(xw + base);
    ushort4 av = *(const ushort4*)(attn + base);
    float tx = bf2f(xv.x) + bf2f(av.x);
    float ty = bf2f(xv.y) + bf2f(av.y);
    float tz = bf2f(xv.z) + bf2f(av.z);
    float tw = bf2f(xv.w) + bf2f(av.w);
    float mean = wave_sum64(tx + ty + tz + tw) * (1.f / 256.f);
    float dx = tx - mean, dy = ty - mean, dz = tz - mean, dw = tw - mean;
    float var = wave_sum64(dx * dx + dy * dy + dz * dz + dw * dw) * (1.f / 256.f);
    float rstd = rsqrtf(var + 1e-5f);
    float4 gg = *(const float4*)(g + c0);
    float4 bb = *(const float4*)(b + c0);
    __hip_bfloat16 ob[4] = { F2B(dx * rstd * gg.x + bb.x), F2B(dy * rstd * gg.y + bb.y),
                             F2B(dz * rstd * gg.z + bb.z), F2B(dw * rstd * gg.w + bb.w) };
    *(ushort4*)((__hip_bfloat16*)a2 + base) = *(const ushort4*)ob;
}

__global__ __launch_bounds__(256) void ln2_kernel(
    const float* __restrict__ xres,
    const float* __restrict__ g, const float* __restrict__ b,
    __hip_bfloat16* __restrict__ hin) {
    const int lane = threadIdx.x & 63;
    const int r = blockIdx.x * 4 + (threadIdx.x >> 6);
    const int c0 = lane * 4;
    float4 v = *(const float4*)(xres + (size_t)r * CDIM + c0);
    float mean = wave_sum64(v.x + v.y + v.z + v.w) * (1.f / 256.f);
    float dx = v.x - mean, dy = v.y - mean, dz = v.z - mean, dw = v.w - mean;
    float var = wave_sum64(dx * dx + dy * dy + dz * dz + dw * dw) * (1.f / 256.f);
    float rstd = rsqrtf(var + 1e-5f);
    float4 gg = *(const float4*)(g + c0);
    float4 bb = *(const float4*)(b + c0);
    __hip_bfloat16 ob[4] = { F2B(dx * rstd * gg.x + bb.x), F2B(dy * rstd * gg.y + bb.y),
                             F2B(dz * rstd * gg.z + bb.z), F2B(dw * rstd * gg.w + bb.w) };
    *(ushort4*)(hin + (size_t)r * CDIM + c0) = *(const ushort4*)ob;
}

// ---------------- fused sampling: prep (softmax + corner wgt/idx) + LDS gather ----------------
// One block per window. value window (98x256 bf16 = 49 KB) + corner weights
// (98x8x32 f16 = 49 KB) + indices (24.5 KB) all live in LDS (125 KB total).

__global__ __launch_bounds__(512) void sample_fused(
    const __half* __restrict__ offaw,          // M x 128 (96 off | 32 aw), f16
    const __hip_bfloat16* __restrict__ value,  // M x 256
    __hip_bfloat16* __restrict__ ai) {         // M x 256
    __shared__ __align__(16) __hip_bfloat16 vs[98 * 256];   // 50176 B
    __shared__ __align__(16) __half ws[98 * 8 * 32];        // 50176 B
    __shared__ __align__(16) unsigned char isb[98 * 8 * 32]; // 25088 B
    const int tid = threadIdx.x;
    const int w = blockIdx.x;

    // Phase A: stage value window into LDS (3136 x uint4)
    {
        const uint4* vsrc = (const uint4*)(value + (size_t)w * 98 * CDIM);
        uint4* vdst = (uint4*)vs;
#pragma unroll 2
        for (int i = tid; i < 98 * CDIM / 8; i += 512) vdst[i] = vsrc[i];
    }

    // Phase B: per (row,head) softmax over 4 points + 32 corner weights/indices
    for (int u = tid; u < 98 * 8; u += 512) {
        int r = u >> 3, h = u & 7;
        int z = r / 49, n2 = r - z * 49, yy = n2 / 7, xx = n2 - yy * 7;
        const __half* orow = offaw + ((size_t)w * 98 + r) * 128;
        float l0 = __half2float(orow[96 + h * 4 + 0]);
        float l1 = __half2float(orow[96 + h * 4 + 1]);
        float l2 = __half2float(orow[96 + h * 4 + 2]);
        float l3 = __half2float(orow[96 + h * 4 + 3]);
        float mx = fmaxf(fmaxf(l0, l1), fmaxf(l2, l3));
        float e[4];
        e[0] = __expf(l0 - mx); e[1] = __expf(l1 - mx); e[2] = __expf(l2 - mx); e[3] = __expf(l3 - mx);
        float inv = 1.f / (e[0] + e[1] + e[2] + e[3]);
        __half wl[32];
        unsigned char il[32];
#pragma unroll
        for (int p = 0; p < 4; ++p) {
            float ox = __half2float(orow[h * 12 + p * 3 + 0]);
            float oy = __half2float(orow[h * 12 + p * 3 + 1]);
            float oz = __half2float(orow[h * 12 + p * 3 + 2]);
            float px = (float)xx + ox, py = (float)yy + oy, pz = (float)z + oz;
            float fx0 = floorf(px), fy0 = floorf(py), fz0 = floorf(pz);
            int ix = (int)fx0, iy = (int)fy0, iz = (int)fz0;
            float fx = px - fx0, fy = py - fy0, fz = pz - fz0;
            float wp = e[p] * inv;
            int j = 0;
#pragma unroll
            for (int dz = 0; dz < 2; ++dz) {
                int zi = iz + dz;
                float wz = dz ? fz : 1.f - fz;
#pragma unroll
                for (int dy = 0; dy < 2; ++dy) {
                    int yi = iy + dy;
                    float wy = dy ? fy : 1.f - fy;
#pragma unroll
                    for (int dx = 0; dx < 2; ++dx) {
                        int xi = ix + dx;
                        float wxw = dx ? fx : 1.f - fx;
                        bool valid = (zi >= 0) & (zi < 2) & (yi >= 0) & (yi < 7) & (xi >= 0) & (xi < 7);
                        float wc = valid ? wp * wz * wy * wxw : 0.f;
                        int zc = min(max(zi, 0), 1), yc = min(max(yi, 0), 6), xc = min(max(xi, 0), 6);
                        wl[p * 8 + j] = __float2half(wc);
                        il[p * 8 + j] = (unsigned char)(zc * 49 + yc * 7 + xc);
                        ++j;
                    }
                }
            }
        }
        uint4* wd = (uint4*)(ws + (size_t)u * 32);
        const uint4* ws4 = (const uint4*)wl;
#pragma unroll
        for (int q = 0; q < 4; ++q) wd[q] = ws4[q];
        uint4* idd = (uint4*)(isb + (size_t)u * 32);
        const uint4* is4 = (const uint4*)il;
#pragma unroll
        for (int q = 0; q < 2; ++q) idd[q] = is4[q];
    }
    __syncthreads();

    // Phase C: gather + weighted sum, 4 channels/thread, 8 rows per pass
    const int c4 = tid & 63;
    const int h = c4 >> 3;
    const int c0 = c4 * 4;
    for (int r = tid >> 6; r < 98; r += 8) {
        const __half* wrow = ws + ((size_t)((r << 3) + h)) * 32;
        const unsigned char* irow = isb + ((size_t)((r << 3) + h)) * 32;
        float a0 = 0.f, a1 = 0.f, a2 = 0.f, a3 = 0.f;
#pragma unroll
        for (int p = 0; p < 4; ++p) {
            uint4 wq = *(const uint4*)(wrow + p * 8);
            uint2 iq = *(const uint2*)(irow + p * 8);
            const __half* wh = (const __half*)&wq;
            const unsigned char* ib = (const unsigned char*)&iq;
#pragma unroll
            for (int j = 0; j < 8; ++j) {
                float wj = __half2float(wh[j]);
                ushort4 v = *(const ushort4*)(vs + (size_t)ib[j] * CDIM + c0);
                a0 += wj * bf2f(v.x);
                a1 += wj * bf2f(v.y);
                a2 += wj * bf2f(v.z);
                a3 += wj * bf2f(v.w);
            }
        }
        __hip_bfloat16 ob[4] = { F2B(a0), F2B(a1), F2B(a2), F2B(a3) };
        *(ushort4*)(ai + ((size_t)w * 98 + r) * CDIM + c0) = *(const ushort4*)ob;
    }
}

// ---------------- MFMA GEMM (double-buffered async staging) ----------------
// C[M,N] = A[M,K] * Bt[N,K]^T + bias, epilogue per MODE.

template <int MODE>
__global__ __launch_bounds__(256) void gemm_bt(
    const __hip_bfloat16* __restrict__ A,
    const __hip_bfloat16* __restrict__ Bt,
    const int N, const int K,
    const float* __restrict__ bias0,
    const float* __restrict__ bias1,
    const float* __restrict__ bias2,
    void* C,
    void* extra,
    const void* extra2,
    const float* __restrict__ csum) {
    __shared__ __align__(16) __hip_bfloat16 As[2][128 * 32];
    __shared__ __align__(16) __hip_bfloat16 Bs[2][128 * 32];
    const int tid  = threadIdx.x;
    const int lane = tid & 63;
    const int wave = tid >> 6;
    const int wm = (wave >> 1) * 64;
    const int wn = (wave & 1) * 64;
    const int row0 = blockIdx.x * 128;
    const int col0 = blockIdx.y * 128;
    const int l15 = lane & 15;
    const int quad = lane >> 4;

    floatx4 acc[4][4] = {};

    const int sr = tid >> 2;
    const int sk = (tid & 3) * 8;

    const __hip_bfloat16* Ab = A + (size_t)row0 * K + sr * (size_t)K + sk;
    const __hip_bfloat16* Bb = Bt + (size_t)col0 * K + sr * (size_t)K + sk;
    const size_t half64 = (size_t)64 * K;

    auto stage = [&](int buf, int k0) {
#if HAS_GLL
        __builtin_amdgcn_global_load_lds(
            (const __attribute__((address_space(1))) void*)(Ab + k0),
            (__attribute__((address_space(3))) void*)(&As[buf][sr * 32 + sk]), 16, 0, 0);
        __builtin_amdgcn_global_load_lds(
            (const __attribute__((address_space(1))) void*)(Ab + half64 + k0),
            (__attribute__((address_space(3))) void*)(&As[buf][(sr + 64) * 32 + sk]), 16, 0, 0);
        __builtin_amdgcn_global_load_lds(
            (const __attribute__((address_space(1))) void*)(Bb + k0),
            (__attribute__((address_space(3))) void*)(&Bs[buf][sr * 32 + sk]), 16, 0, 0);
        __builtin_amdgcn_global_load_lds(
            (const __attribute__((address_space(1))) void*)(Bb + half64 + k0),
            (__attribute__((address_space(3))) void*)(&Bs[buf][(sr + 64) * 32 + sk]), 16, 0, 0);
#else
        *reinterpret_cast<uint4*>(&As[buf][sr * 32 + sk]) = *reinterpret_cast<const uint4*>(Ab + k0);
        *reinterpret_cast<uint4*>(&As[buf][(sr + 64) * 32 + sk]) = *reinterpret_cast<const uint4*>(Ab + half64 + k0);
        *reinterpret_cast<uint4*>(&Bs[buf][sr * 32 + sk]) = *reinterpret_cast<const uint4*>(Bb + k0);
        *reinterpret_cast<uint4*>(&Bs[buf][(sr + 64) * 32 + sk]) = *reinterpret_cast<const uint4*>(Bb + half64 + k0);
#endif
    };

    const int nk = K >> 5;
    stage(0, 0);
    for (int t = 0; t < nk; ++t) {
        __syncthreads();                       // drains vmcnt: buffer t&1 is ready
        if (t + 1 < nk) stage((t + 1) & 1, (t + 1) * 32);   // async fill of other buffer
        const __hip_bfloat16* Asb = As[t & 1];
        const __hip_bfloat16* Bsb = Bs[t & 1];
        bf16x8 af[4], bfg[4];
#pragma unroll
        for (int i = 0; i < 4; ++i)
            af[i] = *reinterpret_cast<const bf16x8*>(&Asb[(wm + i * 16 + l15) * 32 + quad * 8]);
#pragma unroll
        for (int j = 0; j < 4; ++j)
            bfg[j] = *reinterpret_cast<const bf16x8*>(&Bsb[(wn + j * 16 + l15) * 32 + quad * 8]);
#pragma unroll
        for (int i = 0; i < 4; ++i)
#pragma unroll
            for (int j = 0; j < 4; ++j)
                acc[i][j] = __builtin_amdgcn_mfma_f32_16x16x32_bf16(af[i], bfg[j], acc[i][j], 0, 0, 0);
    }

#pragma unroll
    for (int i = 0; i < 4; ++i) {
#pragma unroll
        for (int j = 0; j < 4; ++j) {
#pragma unroll
            for (int rr = 0; rr < 4; ++rr) {
                int row = row0 + wm + i * 16 + quad * 4 + rr;
                int col = col0 + wn + j * 16 + l15;
                float v = acc[i][j][rr];
                if constexpr (MODE == MODE_BF16) {
                    v += bias0[col];
                    ((__hip_bfloat16*)C)[(size_t)row * N + col] = F2B(v);
                } else if constexpr (MODE == MODE_VALOFFAW) {
                    // cols [0,256): value (bf16, ld 256). cols [256,384): offaw (f16, ld 128)
                    if (col < 256) {
                        v += bias0[col];
                        ((__hip_bfloat16*)C)[(size_t)row * 256 + col] = F2B(v);
                    } else {
                        int c2 = col - 256;
                        const float* diag = (const float*)extra2;
                        v += (c2 < 96 ? bias1[c2] : bias2[c2 - 96]);
                        v += diag[row] * csum[c2];   // q = xw + diag folded in
                        ((__half*)extra)[(size_t)row * 128 + c2] = __float2half(v);
                    }
                } else if constexpr (MODE == MODE_REVERSE) {
                    v += bias0[col];
                    int tok; win_decode(row, tok);
                    const float* xin = (const float*)extra2;   // original x, f32
                    ((float*)C)[(size_t)tok * CDIM + col] = xin[(size_t)tok * CDIM + col] + v;
                } else if constexpr (MODE == MODE_GELU) {
                    v += bias0[col];
                    // gelu_tanh == v * sigmoid(2t)
                    float t2 = 1.5957691216057308f * (v + 0.044715f * v * v * v);
                    v = v / (1.f + __expf(-t2));
                    ((__hip_bfloat16*)C)[(size_t)row * N + col] = F2B(v);
                } else {  // MODE_FC2: out = xres + A@fc2 + b, f32 in-place on d_out
                    v += bias0[col];
                    const float* xres = (const float*)extra2;
                    v += xres[(size_t)row * CDIM + col];
                    ((float*)C)[(size_t)row * CDIM + col] = v;
                }
            }
        }
    }
}

// ---------------- host launcher ----------------

extern "C" void kernel_launch(void* const* d_in, const int* in_sizes, int n_in,
                              void* d_out, int out_size, void* d_ws, size_t ws_size,
                              hipStream_t stream) {
    const float* x      = (const float*)d_in[0];
    const float* mask   = (const float*)d_in[1];
    const float* n1g    = (const float*)d_in[2];
    const float* n1b    = (const float*)d_in[3];
    const float* val_w  = (const float*)d_in[4];
    const float* val_b  = (const float*)d_in[5];
    const float* off_w  = (const float*)d_in[6];
    const float* off_b  = (const float*)d_in[7];
    const float* aw_w   = (const float*)d_in[8];
    const float* aw_b   = (const float*)d_in[9];
    const float* out_w  = (const float*)d_in[10];
    const float* out_b  = (const float*)d_in[11];
    const float* ang    = (const float*)d_in[12];
    const float* anb    = (const float*)d_in[13];
    const float* proj_w = (const float*)d_in[14];
    const float* proj_b = (const float*)d_in[15];
    const float* n2g    = (const float*)d_in[16];
    const float* n2b    = (const float*)d_in[17];
    const float* fc1_w  = (const float*)d_in[18];
    const float* fc1_b  = (const float*)d_in[19];
    const float* fc2_w  = (const float*)d_in[20];
    const float* fc2_b  = (const float*)d_in[21];

    char* ws = (char*)d_ws;
    size_t o = 0;
    auto alloc = [&](size_t bytes) {
        size_t r = o;
        o += (bytes + 255) & ~(size_t)255;
        return r;
    };
    const size_t M = MROWS;
    const size_t REGION_B = M * 128 * 2 + M * 256 * 2 + M * 256 * 2;  // offaw + ai + slack (hbuf reuse)

    __hip_bfloat16* valT    = (__hip_bfloat16*)(ws + alloc(256 * 256 * 2));
    __hip_bfloat16* offawT  = (__hip_bfloat16*)(ws + alloc(128 * 256 * 2));  // contiguous after valT
    __hip_bfloat16* outT    = (__hip_bfloat16*)(ws + alloc(256 * 256 * 2));
    __hip_bfloat16* projT   = (__hip_bfloat16*)(ws + alloc(256 * 256 * 2));
    __hip_bfloat16* fc1T    = (__hip_bfloat16*)(ws + alloc(1024 * 256 * 2));
    __hip_bfloat16* fc2T    = (__hip_bfloat16*)(ws + alloc(256 * 1024 * 2));
    float*          csum    = (float*)(ws + alloc(128 * 4));
    float*          diag    = (float*)(ws + alloc(M * 4));
    char*           slab1   = ws + alloc(M * 256 * 2);                 // xw -> a2 -> hin
    char*           region  = ws + alloc(REGION_B);                    // multi-use
    (void)ws_size; (void)in_sizes; (void)n_in; (void)out_size;

    __hip_bfloat16* xw    = (__hip_bfloat16*)slab1;
    __hip_bfloat16* a2    = (__hip_bfloat16*)slab1;
    __hip_bfloat16* hin   = (__hip_bfloat16*)slab1;
    __half*         offaw = (__half*)region;                           // M x 128 f16
    __hip_bfloat16* ai    = (__hip_bfloat16*)(region + M * 128 * 2);   // M x 256 bf16
    __hip_bfloat16* hbuf  = (__hip_bfloat16*)region;                   // MLP chunk activation (offaw/ai dead)
    __hip_bfloat16* value = (__hip_bfloat16*)d_out;                    // bf16 scratch
    __hip_bfloat16* attn  = (__hip_bfloat16*)d_out;                    // bf16 scratch
    float*          xres  = (float*)d_out;                             // f32 trunk

    dim3 blk(256);
    hipLaunchKernelGGL(transpose_all, dim3(2944), blk, 0, stream,
                       val_w, off_w, aw_w, out_w, proj_w, fc1_w, fc2_w,
                       valT, offawT, outT, projT, fc1T, fc2T);
    hipLaunchKernelGGL(diag_colsum_kernel, dim3(MROWS / 256 + 1), blk, 0, stream,
                       mask, diag, offawT, csum);

    // 1. xw = LN1(x) windowed          (slab1)
    hipLaunchKernelGGL(ln1_kernel, dim3(MROWS / 4), blk, 0, stream, x, n1g, n1b, xw);
    // 2+3 merged. N=384 over [valT|offawT]: value -> d_out bf16, offaw -> region f16
    hipLaunchKernelGGL((gemm_bt<MODE_VALOFFAW>), dim3(MROWS / 128, 3), blk, 0, stream,
                       xw, valT, 384, 256, val_b, off_b, aw_b,
                       (void*)value, (void*)offaw, (const void*)diag, csum);
    // 4. ai = fused prep + LDS-gather sample(value)   (region)
    hipLaunchKernelGGL(sample_fused, dim3(MROWS / 98), dim3(512), 0, stream,
                       offaw, value, ai);
    // 5. attn = ai @ out_w + out_b     (d_out bf16 scratch; value dead)
    hipLaunchKernelGGL((gemm_bt<MODE_BF16>), dim3(MROWS / 128, 2), blk, 0, stream,
                       ai, outT, 256, 256, out_b, (const float*)nullptr, (const float*)nullptr,
                       (void*)attn, (void*)nullptr, (const void*)nullptr, (const float*)nullptr);
    // 6. a2 = LN(xw + attn)            (slab1, in-place over xw)
    hipLaunchKernelGGL(ln_a_kernel, dim3(MROWS / 4), blk, 0, stream, xw, attn, ang, anb, a2);
    // 7. xres = x + reverse(a2 @ proj + b)   (d_out f32, token order; attn dead)
    hipLaunchKernelGGL((gemm_bt<MODE_REVERSE>), dim3(MROWS / 128, 2), blk, 0, stream,
                       a2, projT, 256, 256, proj_b, (const float*)nullptr, (const float*)nullptr,
                       (void*)xres, (void*)nullptr, (const void*)x, (const float*)nullptr);
    // 8. hin = LN2(xres)               (slab1; a2 dead)
    hipLaunchKernelGGL(ln2_kernel, dim3(MROWS / 4), blk, 0, stream, xres, n2g, n2b, hin);
    // 9. MLP in 2 row-chunks; fc2 adds xres in-place on d_out (f32, same element)
    for (int c = 0; c < 2; ++c) {
        const __hip_bfloat16* hin_c = hin + (size_t)c * MCHUNK * 256;
        float*                out_c = (float*)d_out + (size_t)c * MCHUNK * 256;
        hipLaunchKernelGGL((gemm_bt<MODE_GELU>), dim3(MCHUNK / 128, 8), blk, 0, stream,
                           hin_c, fc1T, 1024, 256, fc1_b, (const float*)nullptr, (const float*)nullptr,
                           (void*)hbuf, (void*)nullptr, (const void*)nullptr, (const float*)nullptr);
        hipLaunchKernelGGL((gemm_bt<MODE_FC2>), dim3(MCHUNK / 128, 2), blk, 0, stream,
                           hbuf, fc2T, 256, 1024, fc2_b, (const float*)nullptr, (const float*)nullptr,
                           (void*)out_c, (void*)nullptr, (const void*)out_c, (const float*)nullptr);
    }
}